// Round 8
// baseline (1697.426 us; speedup 1.0000x reference)
//
#include <hip/hip_runtime.h>
#include <math.h>

// ---------------------------------------------------------------------------
// TransformerContinuous: B=8, Lx=512, n_w=384, S=896, D=1024, H=16, hd=64,
// NL=4, FF=4096, HAM=144.
// Round 14: gemm8p restored to round-6 8-phase (best measured for BN=256;
// round-7 2-phase was -2.4%). QKV moved to gemm2p<MODE=2> BN=128: grid
// 336 -> 672 blocks fixes 65.6% -> 87.5% CU fill (1 block/CU at 96-128KB
// LDS; 336 blocks = 2 rounds with an 80-block tail). attn QBLK=128 and the
// rest unchanged from round-6 best (1638 us).
// ---------------------------------------------------------------------------

#define B_      8
#define LX_     512
#define NW_     384
#define S_      896
#define D_      1024
#define H_      16
#define HD_     64
#define FF_     4096
#define HAM_    144

#define RMS_SCALE 0.9999500037496876f            // 1/sqrt(1.0001)
#define PE_C     (-6.907755278982137f / 1024.0f) // -ln(1000)/D

typedef __bf16 bf16x4 __attribute__((ext_vector_type(4)));
typedef __bf16 bf16x8 __attribute__((ext_vector_type(8)));
typedef float  f32x4  __attribute__((ext_vector_type(4)));

static __device__ __forceinline__ float nan0(float v) { return (v != v) ? 0.0f : v; }

static __device__ __forceinline__ void async_copy16(const __bf16* g, __bf16* l) {
    __builtin_amdgcn_global_load_lds(
        (const __attribute__((address_space(1))) void*)g,
        (__attribute__((address_space(3))) void*)l, 16, 0, 0);
}

// tanh-form GELU, one v_exp_f32; |err| vs exact-erf GELU < ~3e-4 (sub-bf16-ulp)
static __device__ __forceinline__ float fast_gelu(float x) {
    float x3 = x * x * x;
    float z = 0.7978845608028654f * x + 0.035677408136300125f * x3;
    float az = fabsf(z);
    float e = __expf(2.0f * az);
    float t = 1.0f - 2.0f / (e + 1.0f);
    t = (z < 0.0f) ? -t : t;
    return 0.5f * x * (1.0f + t);
}

// ---------------- fused fp32 -> bf16 conversion of 4 weight tensors ---------
__global__ __launch_bounds__(256) void convert4_kernel(
        const float* __restrict__ s0, const float* __restrict__ s1,
        const float* __restrict__ s2, const float* __restrict__ s3,
        __bf16* __restrict__ d0, __bf16* __restrict__ d1,
        __bf16* __restrict__ d2, __bf16* __restrict__ d3) {
    int blk = blockIdx.x;
    const float* src; __bf16* dst; int base;
    if (blk < 3072)      { src = s0; dst = d0; base = blk; }
    else if (blk < 4096) { src = s1; dst = d1; base = blk - 3072; }
    else if (blk < 8192) { src = s2; dst = d2; base = blk - 4096; }
    else                 { src = s3; dst = d3; base = blk - 8192; }
    int i = (base * 256 + threadIdx.x) * 4;
    float4 v = *(const float4*)&src[i];
    bf16x4 o = {(__bf16)v.x, (__bf16)v.y, (__bf16)v.z, (__bf16)v.w};
    *(bf16x4*)&dst[i] = o;
}

// ---------------- transpose W_nail (1024x63) -> W_nailT (63x1024) -----------
__global__ __launch_bounds__(256) void transpose_nail_kernel(
        const float* __restrict__ W_nail, float* __restrict__ WT) {
    int i = blockIdx.x * 256 + threadIdx.x;      // 63*1024 = 64512, grid 252
    int d = i & 1023, kk = i >> 10;
    WT[kk * 1024 + d] = W_nail[d * 63 + kk];
}

// ---------------- embed x: 8 rows per block, coalesced W_nailT ---------------
__global__ __launch_bounds__(256) void embed_x_kernel(
        const float* __restrict__ x, const float* __restrict__ WT,
        const float* __restrict__ b_nail, __bf16* __restrict__ tgt_bf,
        int* __restrict__ xmask) {
    int row0 = blockIdx.x * 8;               // 8 rows of (b*512+i)
    int tid = threadIdx.x;
    __shared__ float xn[8][64];
    __shared__ float ts[8];
#pragma unroll
    for (int it = 0; it < 2; ++it) {
        int i = tid + it * 256;              // 0..511
        int r = i >> 6, c = i & 63;
        float vv = x[(size_t)(row0 + r) * 64 + c];
        float v0 = nan0(vv);
        xn[r][c] = fminf(fmaxf(v0 * RMS_SCALE, -5.0f), 5.0f);
        if (c == 0) { ts[r] = v0; xmask[row0 + r] = (vv != vv) ? 1 : 0; }
    }
    __syncthreads();
    int d0 = tid * 4;
    float4 bz = *(const float4*)&b_nail[d0];
    float acc[8][4];
#pragma unroll
    for (int r = 0; r < 8; ++r) {
        acc[r][0] = bz.x; acc[r][1] = bz.y; acc[r][2] = bz.z; acc[r][3] = bz.w;
    }
    for (int k = 0; k < 63; ++k) {
        float4 wv = *(const float4*)&WT[k * 1024 + d0];
#pragma unroll
        for (int r = 0; r < 8; ++r) {
            float xv = xn[r][k + 1];         // block-uniform -> LDS broadcast
            acc[r][0] += xv * wv.x; acc[r][1] += xv * wv.y;
            acc[r][2] += xv * wv.z; acc[r][3] += xv * wv.w;
        }
    }
    float div[4];
#pragma unroll
    for (int j = 0; j < 4; ++j)
        div[j] = __expf((float)((d0 + j) >> 1) * PE_C);
#pragma unroll
    for (int r = 0; r < 8; ++r) {
        int row = row0 + r;
        int b = row >> 9, i = row & 511;
        float t = ts[r];
        bf16x4 ob;
#pragma unroll
        for (int j = 0; j < 4; ++j) {
            float ang = t * div[j];
            float pe = ((d0 + j) & 1) ? __cosf(ang) : __sinf(ang);
            ob[j] = (__bf16)(acc[r][j] + pe);
        }
        *(bf16x4*)&tgt_bf[((size_t)b * S_ + i) * D_ + d0] = ob;
    }
}

// ---------------- embed w: rows (b,j) of w -> tgt rows 512..895 ----------------
__global__ __launch_bounds__(256) void embed_w_kernel(
        const float* __restrict__ w, const float* __restrict__ W_cond,
        const float* __restrict__ b_cond, __bf16* __restrict__ tgt_bf) {
    int row = blockIdx.x;              // b*384 + j
    int b = row / NW_, j = row % NW_;
    const float* wr = w + (long)row * 6;
    float wn[6];
#pragma unroll
    for (int k = 0; k < 6; ++k)
        wn[k] = fminf(fmaxf(nan0(wr[k]) * RMS_SCALE, -5.0f), 5.0f);
    int tid = threadIdx.x;
    int d0 = tid * 4;
    float pos = (float)(LX_ + j);
    bf16x4 ob;
#pragma unroll
    for (int jj = 0; jj < 4; ++jj) {
        int d = d0 + jj;
        float acc = b_cond[d];
        const float* wc = W_cond + (long)d * 6;
#pragma unroll
        for (int k = 0; k < 6; ++k) acc += wn[k] * wc[k];
        float dv = expf((float)(d >> 1) * PE_C);
        float ang = pos * dv;
        ob[jj] = (__bf16)(acc + ((d & 1) ? cosf(ang) : sinf(ang)));
    }
    *(bf16x4*)&tgt_bf[((long)b * S_ + LX_ + j) * D_ + d0] = ob;
}

// ---------------------------------------------------------------------------
// Shared GEMM macros. C[M,N] = A[M,K] @ W[N,K]^T + bias.
//   A frag mi (0..7): row = (mi>>2)*128 + wr*64 + (mi&3)*16
//   B frag ni:  BN=256: row = (ni>>1)*128 + wc*32 + (ni&1)*16
//               BN=128: row = ni*64 + wc*16
// ---------------------------------------------------------------------------

#define LDA(BUF, MH) do {                                                      \
    _Pragma("unroll")                                                          \
    for (int i_ = 0; i_ < 4; ++i_) {                                           \
        const int row_ = (MH) * 128 + wr * 64 + i_ * 16 + frow;                \
        _Pragma("unroll")                                                      \
        for (int k_ = 0; k_ < 2; ++k_)                                         \
            a[i_][k_] = *(const bf16x8*)&As[BUF][row_ * 64 +                   \
                (((quad + k_ * 4) ^ sf) * 8)];                                 \
    }                                                                          \
} while (0)

#define LDB(BUF, NH) do {                                                      \
    _Pragma("unroll")                                                          \
    for (int j_ = 0; j_ < NJ; ++j_) {                                          \
        const int row_ = (BN == 256)                                           \
            ? ((NH) * 128 + j_ * 16 + wc * 32 + frow)                          \
            : ((NH) * 64 + wc * 16 + frow);                                    \
        _Pragma("unroll")                                                      \
        for (int k_ = 0; k_ < 2; ++k_)                                         \
            b[(NH) * NJ + j_][k_] = *(const bf16x8*)&Bs[BUF][row_ * 64 +       \
                (((quad + k_ * 4) ^ sf) * 8)];                                 \
    }                                                                          \
} while (0)

#define MMA(MH, NH) do {                                                       \
    _Pragma("unroll")                                                          \
    for (int i_ = 0; i_ < 4; ++i_)                                             \
        _Pragma("unroll")                                                      \
        for (int j_ = 0; j_ < NJ; ++j_)                                        \
            _Pragma("unroll")                                                  \
            for (int k_ = 0; k_ < 2; ++k_)                                     \
                acc[(MH) * 4 + i_][(NH) * NJ + j_] =                           \
                    __builtin_amdgcn_mfma_f32_16x16x32_bf16(                   \
                        b[(NH) * NJ + j_][k_], a[i_][k_],                      \
                        acc[(MH) * 4 + i_][(NH) * NJ + j_], 0, 0, 0);          \
} while (0)

#define STAGE_A(BUF, H, KT) do {                                               \
    const __bf16* g_ = Ag + (size_t)((H) * 128) * K + ((size_t)(KT) << 6);     \
    async_copy16(g_, &As[BUF][((H) * 128) * 64 + dst8]);                       \
    async_copy16(g_ + ((size_t)K << 6), &As[BUF][((H) * 128 + 64) * 64 + dst8]); \
} while (0)

#define STAGE_B(BUF, H, KT) do {                                               \
    if constexpr (BN == 256) {                                                 \
        const __bf16* g_ = Wg + (size_t)((H) * 128) * K + ((size_t)(KT) << 6); \
        async_copy16(g_, &Bs[BUF][((H) * 128) * 64 + dst8]);                   \
        async_copy16(g_ + ((size_t)K << 6),                                    \
                     &Bs[BUF][((H) * 128 + 64) * 64 + dst8]);                  \
    } else {                                                                   \
        const __bf16* g_ = Wg + (size_t)((H) * 64) * K + ((size_t)(KT) << 6);  \
        async_copy16(g_, &Bs[BUF][((H) * 64) * 64 + dst8]);                    \
    }                                                                          \
} while (0)

#define PHASE_SYNC() do {                                                      \
    __builtin_amdgcn_sched_barrier(0);                                         \
    __builtin_amdgcn_s_barrier();                                              \
    asm volatile("s_waitcnt lgkmcnt(0)" ::: "memory");                         \
    __builtin_amdgcn_sched_barrier(0);                                         \
} while (0)

#define PHASE_END() do {                                                       \
    __builtin_amdgcn_sched_barrier(0);                                         \
    __builtin_amdgcn_s_barrier();                                              \
} while (0)

#define VM_MAIN do {                                                           \
    if constexpr (BN == 256) { asm volatile("s_waitcnt vmcnt(6)" ::: "memory"); } \
    else                     { asm volatile("s_waitcnt vmcnt(4)" ::: "memory"); } \
} while (0)
#define VM_ZERO asm volatile("s_waitcnt vmcnt(0)" ::: "memory")
#define VM_NONE ((void)0)

// 8-phase K-tile for BN=256 (round-6 benched)
#define GTILE(S1, S2, VMOP) do {                                               \
    const int bf_ = t & 1;                                                     \
    LDA(bf_, 0); LDB(bf_, 0);                                                  \
    if (S1) STAGE_A(bf_ ^ 1, 1, t + 1);                                        \
    PHASE_SYNC();                                                              \
    __builtin_amdgcn_s_setprio(1); MMA(0, 0); __builtin_amdgcn_s_setprio(0);   \
    PHASE_END();                                                               \
    LDB(bf_, 1);                                                               \
    if (S2) STAGE_B(bf_, 0, t + 2);                                            \
    PHASE_SYNC();                                                              \
    __builtin_amdgcn_s_setprio(1); MMA(0, 1); __builtin_amdgcn_s_setprio(0);   \
    PHASE_END();                                                               \
    LDA(bf_, 1);                                                               \
    if (S2) STAGE_A(bf_, 0, t + 2);                                            \
    PHASE_SYNC();                                                              \
    __builtin_amdgcn_s_setprio(1); MMA(1, 0); __builtin_amdgcn_s_setprio(0);   \
    PHASE_END();                                                               \
    if (S2) STAGE_B(bf_, 1, t + 2);                                            \
    VMOP;                                                                      \
    PHASE_SYNC();                                                              \
    __builtin_amdgcn_s_setprio(1); MMA(1, 1); __builtin_amdgcn_s_setprio(0);   \
    PHASE_END();                                                               \
} while (0)

// ---------------- 8-phase BN=256 pipelined GEMM (FF1) -----------------------
// MODE 1: bias+GELU
template <int BN, int MODE>
__global__ __launch_bounds__(512, 2) void gemm8p(
        const __bf16* __restrict__ A, const __bf16* __restrict__ W,
        const float* __restrict__ bias,
        __bf16* __restrict__ Cb,
        int M, int N, int K) {
    constexpr int NI = BN / 64;          // per-wave n-frags
    constexpr int NJ = NI / 2;           // n-frags per n-half
    static_assert(BN == 256, "BN");
    __shared__ __attribute__((aligned(16))) __bf16 As[2][256 * 64];
    __shared__ __attribute__((aligned(16))) __bf16 Bs[2][BN * 64];

    const int tid = threadIdx.x;
    const int wave = tid >> 6, lane = tid & 63;
    const int wr = wave >> 2, wc = wave & 3;
    const int frow = lane & 15, quad = lane >> 4;
    const int sf = frow & 7;

    // XCD-chunked block swizzle (nwg % 8 == 0 for all our grids)
    const int nwg = gridDim.x * gridDim.y;
    int orig = blockIdx.y * gridDim.x + blockIdx.x;
    int tile = orig;
    if ((nwg & 7) == 0) tile = (orig & 7) * (nwg >> 3) + (orig >> 3);
    const int m0 = (tile / gridDim.x) * 256;
    const int n0 = (tile % gridDim.x) * BN;

    const int sr = tid >> 3;
    const int scol = ((tid & 7) ^ (sr & 7)) * 8;
    const __bf16* Ag = A + (size_t)(m0 + sr) * K + scol;
    const __bf16* Wg = W + (size_t)(n0 + sr) * K + scol;
    const int dst8 = tid * 8;            // elements; = tid*16 bytes (linear)

    f32x4 acc[8][NI];
#pragma unroll
    for (int i = 0; i < 8; ++i)
#pragma unroll
        for (int j = 0; j < NI; ++j) acc[i][j] = 0.0f;
    bf16x8 a[4][2];
    bf16x8 b[NI][2];

    const int NT = K >> 6;

    STAGE_B(0, 0, 0); STAGE_A(0, 0, 0); STAGE_B(0, 1, 0); STAGE_A(0, 1, 0);
    STAGE_B(1, 0, 1); STAGE_A(1, 0, 1); STAGE_B(1, 1, 1);
    VM_MAIN;                             // tile 0 fully landed
    __builtin_amdgcn_s_barrier();

    int t = 0;
    for (; t < NT - 2; ++t) { GTILE(1, 1, VM_MAIN); }
    GTILE(1, 0, VM_ZERO);
    ++t;
    GTILE(0, 0, VM_NONE);

    // ---------------- epilogue ----------------
#pragma unroll
    for (int ni = 0; ni < NI; ++ni) {
        int cg0 = n0 + (ni >> 1) * 128 + (ni & 1) * 16 + wc * 32 + quad * 4;
        float4 bv = *(const float4*)&bias[cg0];
        float bz[4] = {bv.x, bv.y, bv.z, bv.w};
#pragma unroll
        for (int mi = 0; mi < 8; ++mi) {
            int rg = m0 + (mi >> 2) * 128 + wr * 64 + (mi & 3) * 16 + frow;
            float vv[4];
#pragma unroll
            for (int r = 0; r < 4; ++r) {
                float v = acc[mi][ni][r] + bz[r];
                if (MODE == 1) v = fast_gelu(v);
                vv[r] = v;
            }
            bf16x4 o = {(__bf16)vv[0], (__bf16)vv[1], (__bf16)vv[2], (__bf16)vv[3]};
            *(bf16x4*)&Cb[(size_t)rg * N + cg0] = o;
        }
    }
}

// ---------------- 2-phase BN=128 pipelined GEMM (QKV / Wo / FF2) ------------
// (round-3-benched schedule) Per phase: 16 MFMA. Single vmcnt(4) per K-tile.
// XCD-chunked swizzle. MODE 0: bias -> Cb. MODE 2: bias, split q/k (B,H,S,64),
// V transposed (B,H,64,S).
template <int MODE>
__global__ __launch_bounds__(512, 2) void gemm2p(
        const __bf16* __restrict__ A, const __bf16* __restrict__ W,
        const float* __restrict__ bias, __bf16* __restrict__ Cb,
        __bf16* __restrict__ Cq, __bf16* __restrict__ Ck, __bf16* __restrict__ Cv,
        int M, int N, int K) {
    constexpr int BN = 128;
    constexpr int NI = 2, NJ = 1;
    __shared__ __attribute__((aligned(16))) __bf16 As[2][256 * 64];
    __shared__ __attribute__((aligned(16))) __bf16 Bs[2][128 * 64];

    const int tid = threadIdx.x;
    const int wave = tid >> 6, lane = tid & 63;
    const int wr = wave >> 2, wc = wave & 3;
    const int frow = lane & 15, quad = lane >> 4;
    const int sf = frow & 7;

    // XCD-chunked block swizzle (requires nwg % 8 == 0, true for our grids)
    const int nwg = gridDim.x * gridDim.y;
    int orig = blockIdx.y * gridDim.x + blockIdx.x;
    int tile = orig;
    if ((nwg & 7) == 0) tile = (orig & 7) * (nwg >> 3) + (orig >> 3);
    const int m0 = (tile / gridDim.x) * 256;
    const int n0 = (tile % gridDim.x) * BN;

    const int sr = tid >> 3;
    const int scol = ((tid & 7) ^ (sr & 7)) * 8;
    const __bf16* Ag = A + (size_t)(m0 + sr) * K + scol;
    const __bf16* Wg = W + (size_t)(n0 + sr) * K + scol;
    const int dst8 = tid * 8;

    f32x4 acc[8][NI];
#pragma unroll
    for (int i = 0; i < 8; ++i)
#pragma unroll
        for (int j = 0; j < NI; ++j) acc[i][j] = 0.0f;
    bf16x8 a[4][2];
    bf16x8 b[NI][2];

    const int NT = K >> 6;

#define VM4 asm volatile("s_waitcnt vmcnt(4)" ::: "memory")
#define GTILE2(S1, S2, VMOP) do {                                              \
    const int bf_ = t & 1;                                                     \
    /* P0: read A0 + both B halves; stage a1_{t+1} into other buffer */        \
    LDA(bf_, 0); LDB(bf_, 0); LDB(bf_, 1);                                     \
    if (S1) STAGE_A(bf_ ^ 1, 1, t + 1);                                        \
    PHASE_SYNC();                                                              \
    __builtin_amdgcn_s_setprio(1); MMA(0, 0); MMA(0, 1);                       \
    __builtin_amdgcn_s_setprio(0);                                             \
    PHASE_END();                                                               \
    /* P1: read A1; stage b_{t+2} + a0_{t+2} into this buffer (dead slots) */  \
    LDA(bf_, 1);                                                               \
    if (S2) { STAGE_B(bf_, 0, t + 2); STAGE_B(bf_, 1, t + 2);                  \
              STAGE_A(bf_, 0, t + 2); }                                        \
    VMOP;                                                                      \
    PHASE_SYNC();                                                              \
    __builtin_amdgcn_s_setprio(1); MMA(1, 0); MMA(1, 1);                       \
    __builtin_amdgcn_s_setprio(0);                                             \
    PHASE_END();                                                               \
} while (0)

    // prologue queue: b_0(2), a0_0(2), a1_0(2), b_1(2), a0_1(2)
    STAGE_B(0, 0, 0); STAGE_B(0, 1, 0); STAGE_A(0, 0, 0); STAGE_A(0, 1, 0);
    STAGE_B(1, 0, 1); STAGE_B(1, 1, 1); STAGE_A(1, 0, 1);
    VM4;                                 // drain through a1_0: tile 0 landed
    __builtin_amdgcn_s_barrier();

    int t = 0;
    for (; t < NT - 2; ++t) { GTILE2(1, 1, VM4); }
    GTILE2(1, 0, VM_ZERO);               // drains a1_{NT-1}: last tile landed
    ++t;
    GTILE2(0, 0, VM_NONE);
#undef GTILE2
#undef VM4

    // ---------------- epilogue ----------------
#pragma unroll
    for (int ni = 0; ni < NI; ++ni) {
        int cg0 = n0 + ni * 64 + wc * 16 + quad * 4;
        float4 bv = *(const float4*)&bias[cg0];
        float bz[4] = {bv.x, bv.y, bv.z, bv.w};
#pragma unroll
        for (int mi = 0; mi < 8; ++mi) {
            int rg = m0 + (mi >> 2) * 128 + wr * 64 + (mi & 3) * 16 + frow;
            float vv[4];
#pragma unroll
            for (int r = 0; r < 4; ++r) vv[r] = acc[mi][ni][r] + bz[r];
            if (MODE == 2) {
                int which = cg0 >> 10;        // 0=q 1=k 2=v
                int h = (cg0 & 1023) >> 6;
                int e = cg0 & 63;
                int bb = rg / S_, s = rg % S_;
                if (which == 2) {
                    // V transposed: vt[(b,h,e,s)]
                    size_t vb = ((size_t)bb * H_ + h) * HD_ + e;
#pragma unroll
                    for (int r = 0; r < 4; ++r)
                        Cv[(vb + r) * S_ + s] = (__bf16)vv[r];
                } else {
                    bf16x4 o = {(__bf16)vv[0], (__bf16)vv[1], (__bf16)vv[2], (__bf16)vv[3]};
                    __bf16* dstp = (which == 0) ? Cq : Ck;
                    *(bf16x4*)&dstp[(((size_t)bb * H_ + h) * S_ + s) * HD_ + e] = o;
                }
            } else {
                bf16x4 o = {(__bf16)vv[0], (__bf16)vv[1], (__bf16)vv[2], (__bf16)vv[3]};
                *(bf16x4*)&Cb[(size_t)rg * N + cg0] = o;
            }
        }
    }
}

// ---------------- MFMA flash attention: QBLK=128, 8 waves, 1 barrier/tile ---
// K (b,h,s,64) and Vt (b,h,64,s) staged via global_load_lds (XOR-swizzled,
// double-buffered) once per block, shared by 8 waves. Stage of tile t+1 is
// issued AFTER the top barrier of tile t into the buffer whose reads all
// completed BEFORE that barrier -> single barrier per k-tile.
// Wave-level skip of fully-masked tiles; flavors: x-mask / no-mask / diag.
__global__ __launch_bounds__(512, 4) void attn_mfma(
        const __bf16* __restrict__ q, const __bf16* __restrict__ k,
        const __bf16* __restrict__ vt, const int* __restrict__ xmask,
        __bf16* __restrict__ ctx) {
    __shared__ __attribute__((aligned(16))) __bf16 Ks[2][64 * 64];
    __shared__ __attribute__((aligned(16))) __bf16 Vs[2][64 * 64];
    __shared__ __attribute__((aligned(16))) __bf16 Ps[8][16 * 64];
    __shared__ float mb[LX_];           // x-mask bias: 0 or -inf
    int tid = threadIdx.x;
    int wave = tid >> 6, lane = tid & 63;
    int frow = lane & 15, quad = lane >> 4;
    int f7 = frow & 7, f3 = frow >> 3;
    int sl0 = (quad ^ f7) * 8;          // slot for k-elems 0..31
    int sl1 = ((quad + 4) ^ f7) * 8;    // slot for k-elems 32..63

    // XCD swizzle: 896 blocks = 8 xcd * 112 slots; 16 bh per xcd, 7 qt each.
    int blk = blockIdx.x;
    int xcd = blk & 7, slot = blk >> 3;  // slot 0..111
    int bh = xcd * 16 + slot / 7;
    int qt = slot % 7;
    int b = bh >> 4, h = bh & 15;
    int q0 = qt * 128;
    int q0w = q0 + wave * 16;            // this wave's 16 q-rows start
    size_t base = (size_t)bh * S_ * HD_;   // q,k layout
    size_t vbase = (size_t)bh * HD_ * S_;  // vt layout (same extent)

    for (int i = tid; i < LX_; i += 512)
        mb[i] = xmask[(b << 9) + i] ? -INFINITY : 0.0f;

    const __bf16* qrow = q + base + (size_t)(q0w + frow) * HD_ + quad * 8;
    bf16x8 aq0 = *(const bf16x8*)qrow;
    bf16x8 aq1 = *(const bf16x8*)(qrow + 32);

    f32x4 o[4];
#pragma unroll
    for (int dt = 0; dt < 4; ++dt) o[dt] = 0.0f;
    float mrow[4] = {-INFINITY, -INFINITY, -INFINITY, -INFINITY};
    float lrow[4] = {0.0f, 0.0f, 0.0f, 0.0f};

    int kend = (q0 >= LX_) ? (q0 + 128) : LX_;
    int NT = kend >> 6;

    // staging: thread -> (row tid>>3 of 64, slot tid&7), pre-swizzled col
    int sr = tid >> 3;                   // 0..63
    int kcol = ((tid & 7) ^ (sr & 7)) * 8;
    const __bf16* kg = k + base + (size_t)sr * HD_ + kcol;
    const __bf16* vg = vt + vbase + (size_t)sr * S_ + kcol;

#define ASTAGE(BUF, K0) do {                                                   \
    async_copy16(kg + (size_t)(K0) * HD_, &Ks[BUF][tid * 8]);                  \
    async_copy16(vg + (K0),               &Vs[BUF][tid * 8]);                  \
} while (0)

    ASTAGE(0, 0);
    __syncthreads();    // drains vmcnt: tile 0 landed; mb visible

    for (int t = 0; t < NT; ++t) {
        int buf = t & 1;
        int k0 = t << 6;
        // tile t landed (its 2 loads are the only outstanding vmem)
        asm volatile("s_waitcnt vmcnt(0)" ::: "memory");
        __builtin_amdgcn_s_barrier();    // separates tile t-1 reads from stage
        __builtin_amdgcn_sched_barrier(0);
        if (t + 1 < NT) ASTAGE(buf ^ 1, k0 + 64);   // into dead buffer

        // wave-level skip: fully-masked w-region tile for this wave
        if (k0 < LX_ || q0w + 15 >= k0) {
            // ---- QK^T ----
            f32x4 scr[4];
            __builtin_amdgcn_s_setprio(1);
#pragma unroll
            for (int nt = 0; nt < 4; ++nt) {
                int row = (nt * 16 + frow) * 64;
                bf16x8 bk0 = *(const bf16x8*)&Ks[buf][row + sl0];
                bf16x8 bk1 = *(const bf16x8*)&Ks[buf][row + sl1];
                f32x4 z = 0.0f;
                z = __builtin_amdgcn_mfma_f32_16x16x32_bf16(aq0, bk0, z, 0, 0, 0);
                z = __builtin_amdgcn_mfma_f32_16x16x32_bf16(aq1, bk1, z, 0, 0, 0);
                scr[nt] = z;
            }
            __builtin_amdgcn_s_setprio(0);

            // ---- masked scale, per tile flavor ----
            float tmax[4] = {-INFINITY, -INFINITY, -INFINITY, -INFINITY};
            if (k0 < LX_) {              // x-region cols: x_mask bias only
#pragma unroll
                for (int nt = 0; nt < 4; ++nt) {
                    float bias = mb[k0 + nt * 16 + frow];
#pragma unroll
                    for (int r = 0; r < 4; ++r) {
                        float s = scr[nt][r] * 0.125f + bias;
                        scr[nt][r] = s;
                        tmax[r] = fmaxf(tmax[r], s);
                    }
                }
            } else if (q0w >= k0 + 64) { // strictly below diagonal
#pragma unroll
                for (int nt = 0; nt < 4; ++nt)
#pragma unroll
                    for (int r = 0; r < 4; ++r) {
                        float s = scr[nt][r] * 0.125f;
                        scr[nt][r] = s;
                        tmax[r] = fmaxf(tmax[r], s);
                    }
            } else {                     // diagonal tile: causal
#pragma unroll
                for (int nt = 0; nt < 4; ++nt) {
                    int kj = k0 + nt * 16 + frow;
#pragma unroll
                    for (int r = 0; r < 4; ++r) {
                        float s = scr[nt][r] * 0.125f;
                        if (kj > q0w + quad * 4 + r) s = -INFINITY;
                        scr[nt][r] = s;
                        tmax[r] = fmaxf(tmax[r], s);
                    }
                }
            }
#pragma unroll
            for (int off = 1; off < 16; off <<= 1)
#pragma unroll
                for (int r = 0; r < 4; ++r)
                    tmax[r] = fmaxf(tmax[r], __shfl_xor(tmax[r], off, 64));

            float alpha[4], rsum[4];
#pragma unroll
            for (int r = 0; r < 4; ++r) {
                float nm = fmaxf(mrow[r], tmax[r]);
                alpha[r] = (nm == -INFINITY) ? 1.0f : __expf(mrow[r] - nm);
                mrow[r] = nm;
                rsum[r] = 0.0f;
            }
#pragma unroll
            for (int nt = 0; nt < 4; ++nt) {
#pragma unroll
                for (int r = 0; r < 4; ++r) {
                    float s = scr[nt][r];
                    float p = (s == -INFINITY) ? 0.0f : __expf(s - mrow[r]);
                    rsum[r] += p;
                    // Ps[q_local][col] with col-slot XOR swizzle
                    int ql = quad * 4 + r;
                    int pslot = ((nt * 2 + f3) ^ (ql & 7)) * 8 + f7;
                    Ps[wave][ql * 64 + pslot] = (__bf16)p;
                }
            }
#pragma unroll
            for (int off = 1; off < 16; off <<= 1)
#pragma unroll
                for (int r = 0; r < 4; ++r)
                    rsum[r] += __shfl_xor(rsum[r], off, 64);
#pragma unroll
            for (int r = 0; r < 4; ++r)
                lrow[r] = lrow[r] * alpha[r] + rsum[r];
#pragma unroll
            for (int dt = 0; dt < 4; ++dt)
#pragma unroll
                for (int r = 0; r < 4; ++r)
                    o[dt][r] *= alpha[r];

            // ---- PV ----
            bf16x8 ap0 = *(const bf16x8*)&Ps[wave][frow * 64 + sl0];
            bf16x8 ap1 = *(const bf16x8*)&Ps[wave][frow * 64 + sl1];
            __builtin_amdgcn_s_setprio(1);
#pragma unroll
            for (int dt = 0; dt < 4; ++dt) {
                int row = (dt * 16 + frow) * 64;
                bf16x8 bv0 = *(const bf16x8*)&Vs[buf][row + sl0];
                bf16x8 bv1 = *(const bf16x8*)&Vs[buf][row + sl1];
                o[dt] = __builtin_amdgcn_mfma_f32_16x16x32_bf16(ap0, bv0, o[dt], 0, 0, 0);
                o[dt] = __builtin_amdgcn_mfma_f32_16x16x32_bf16(ap1, bv1, o[dt], 0, 0, 0);
            }
            __builtin_amdgcn_s_setprio(0);
        }
        __builtin_amdgcn_sched_barrier(0);
    }
#undef ASTAGE

#pragma unroll
    for (int r = 0; r < 4; ++r) {
        float inv = (lrow[r] > 0.0f) ? 1.0f / lrow[r] : 0.0f;
        int qg = q0w + quad * 4 + r;
        size_t ob = ((size_t)b * S_ + qg) * D_ + h * HD_;
#pragma unroll
        for (int dt = 0; dt < 4; ++dt)
            ctx[ob + dt * 16 + frow] = (__bf16)(o[dt][r] * inv);
    }
}

// ---------------- fused residual add + LayerNorm (bf16 stream) --------------
__global__ __launch_bounds__(256) void add_ln_kernel(
        __bf16* __restrict__ xs_bf, const __bf16* __restrict__ o,
        const float* __restrict__ g, const float* __restrict__ bb) {
    long row = blockIdx.x;
    __bf16* xr = xs_bf + row * D_;
    const __bf16* orr = o + row * D_;
    int tid = threadIdx.x;
    bf16x4 a4 = *(const bf16x4*)&xr[tid * 4];
    bf16x4 b4v = *(const bf16x4*)&orr[tid * 4];
    float vv[4];
#pragma unroll
    for (int j = 0; j < 4; ++j) vv[j] = (float)a4[j] + (float)b4v[j];
    float s = vv[0] + vv[1] + vv[2] + vv[3];
    __shared__ float red[4];
    __shared__ float stat;
#pragma unroll
    for (int off = 32; off; off >>= 1) s += __shfl_down(s, off, 64);
    if ((tid & 63) == 0) red[tid >> 6] = s;
    __syncthreads();
    if (tid == 0) stat = (red[0] + red[1] + red[2] + red[3]) * (1.0f / 1024.0f);
    __syncthreads();
    float mean = stat;
    float d[4];
    float s2 = 0.0f;
#pragma unroll
    for (int j = 0; j < 4; ++j) { d[j] = vv[j] - mean; s2 += d[j] * d[j]; }
    __syncthreads();
#pragma unroll
    for (int off = 32; off; off >>= 1) s2 += __shfl_down(s2, off, 64);
    if ((tid & 63) == 0) red[tid >> 6] = s2;
    __syncthreads();
    if (tid == 0) stat = (red[0] + red[1] + red[2] + red[3]) * (1.0f / 1024.0f);
    __syncthreads();
    float inv = 1.0f / sqrtf(stat + 1e-5f);
    float4 gg = *(const float4*)&g[tid * 4];
    float4 bv = *(const float4*)&bb[tid * 4];
    float g4[4] = {gg.x, gg.y, gg.z, gg.w};
    float b4[4] = {bv.x, bv.y, bv.z, bv.w};
    bf16x4 ob;
#pragma unroll
    for (int j = 0; j < 4; ++j) ob[j] = (__bf16)(d[j] * inv * g4[j] + b4[j]);
    *(bf16x4*)&xr[tid * 4] = ob;
}

// ---------------- head: (8,1024) @ W_ham^T + b_ham -> (8,144) ----------------
__global__ __launch_bounds__(256) void head_kernel(
        const __bf16* __restrict__ tgt_bf, const float* __restrict__ W_ham,
        const float* __restrict__ b_ham, float* __restrict__ out) {
    int b = blockIdx.x;
    int tid = threadIdx.x;
    __shared__ float xr[D_];
    const __bf16* row = tgt_bf + ((long)b * S_ + (S_ - 1)) * D_;
    for (int i = tid; i < D_; i += 256) xr[i] = (float)row[i];
    __syncthreads();
    for (int n = tid; n < HAM_; n += 256) {
        float acc = b_ham[n];
        const float* wr = W_ham + (long)n * D_;
        for (int kk = 0; kk < D_; ++kk) acc += xr[kk] * wr[kk];
        out[b * HAM_ + n] = acc;
    }
}

// ---------------- loss: mean((head_out - (y - w_last))^2) --------------------
__global__ __launch_bounds__(256) void loss_kernel(
        const float* __restrict__ head_out, const float* __restrict__ y,
        const float* __restrict__ w, float* __restrict__ out) {
    int tid = threadIdx.x;
    float acc = 0.0f;
    for (int i = tid; i < B_ * HAM_; i += 256) {
        int b = i / HAM_, r = i % HAM_;
        float w_last = w[((long)b * 16 + 15) * HAM_ + r];
        float resid = y[i] - w_last;
        float dd = head_out[i] - resid;
        acc += dd * dd;
    }
    __shared__ float red[4];
#pragma unroll
    for (int off = 32; off; off >>= 1) acc += __shfl_down(acc, off, 64);
    if ((tid & 63) == 0) red[tid >> 6] = acc;
    __syncthreads();
    if (tid == 0)
        out[0] = (red[0] + red[1] + red[2] + red[3]) * (1.0f / (B_ * HAM_));
}

// ---------------------------------------------------------------------------
extern "C" void kernel_launch(void* const* d_in, const int* in_sizes, int n_in,
                              void* d_out, int out_size, void* d_ws, size_t ws_size,
                              hipStream_t stream) {
    const float* x      = (const float*)d_in[0];
    const float* w      = (const float*)d_in[1];
    const float* y      = (const float*)d_in[2];
    const float* W_nail = (const float*)d_in[3];
    const float* b_nail = (const float*)d_in[4];
    const float* W_cond = (const float*)d_in[5];
    const float* b_cond = (const float*)d_in[6];
    const float* Wqkv   = (const float*)d_in[7];
    const float* bqkv   = (const float*)d_in[8];
    const float* Wo     = (const float*)d_in[9];
    const float* bo     = (const float*)d_in[10];
    const float* ln1_g  = (const float*)d_in[11];
    const float* ln1_b  = (const float*)d_in[12];
    const float* ln2_g  = (const float*)d_in[13];
    const float* ln2_b  = (const float*)d_in[14];
    const float* W1     = (const float*)d_in[15];
    const float* b1     = (const float*)d_in[16];
    const float* W2     = (const float*)d_in[17];
    const float* b2     = (const float*)d_in[18];
    const float* W_ham  = (const float*)d_in[19];
    const float* b_ham  = (const float*)d_in[20];

    float* ws = (float*)d_ws;
    const long SEG = (long)B_ * S_ * D_;            // 7,340,032 floats
    float*  W_nailT = ws;                           // 64512 floats (in old tgt slot)
    __bf16* tmp_bf = (__bf16*)(ws + SEG);           // [SEG, 1.5SEG)
    __bf16* tgt_bf = (__bf16*)(ws + 2 * SEG);       // [2SEG, 2.5SEG)
    __bf16* ctx_bf = (__bf16*)(ws + 2 * SEG + SEG / 2);      // [2.5SEG, 3SEG)
    __bf16* qb     = (__bf16*)(ws + 3 * SEG);                // [3SEG, 3.5SEG)
    __bf16* kb     = (__bf16*)(ws + 3 * SEG + SEG / 2);      // [3.5SEG, 4SEG)
    __bf16* vb     = (__bf16*)(ws + 4 * SEG);                // [4SEG, 4.5SEG) (transposed)
    __bf16* ffh_bf = (__bf16*)(ws + 2 * SEG + SEG / 2);      // overlays ctx|q|k|v
    __bf16* wbf    = (__bf16*)(ws + 4 * SEG + SEG / 2);      // 12.58M bf16
    int*    xmask    = (int*)(ws + 4 * SEG + SEG / 2 + 6291456);
    float*  head_out = ws + 4 * SEG + SEG / 2 + 6291456 + 4096;

    __bf16* wqkv_bf = wbf;
    __bf16* wo_bf   = wbf + 3145728;
    __bf16* w1_bf   = wbf + 4194304;
    __bf16* w2_bf   = wbf + 8388608;

    const int M = B_ * S_;                          // 7168

    transpose_nail_kernel<<<252, 256, 0, stream>>>(W_nail, W_nailT);
    embed_x_kernel<<<B_ * LX_ / 8, 256, 0, stream>>>(x, W_nailT, b_nail, tgt_bf, xmask);
    embed_w_kernel<<<B_ * NW_, 256, 0, stream>>>(w, W_cond, b_cond, tgt_bf);

    for (int L = 0; L < 4; ++L) {
        const int NQ = 3 * D_ * D_, NO = D_ * D_, N1 = FF_ * D_, N2 = D_ * FF_;
        convert4_kernel<<<12288, 256, 0, stream>>>(
            Wqkv + (size_t)L * NQ, Wo + (size_t)L * NO,
            W1 + (size_t)L * N1, W2 + (size_t)L * N2,
            wqkv_bf, wo_bf, w1_bf, w2_bf);

        gemm2p<2><<<dim3(3 * D_ / 128, M / 256), 512, 0, stream>>>(
            tgt_bf, wqkv_bf, bqkv + (size_t)L * 3 * D_,
            nullptr, qb, kb, vb, M, 3 * D_, D_);
        attn_mfma<<<B_ * H_ * (S_ / 128), 512, 0, stream>>>(qb, kb, vb, xmask, ctx_bf);
        gemm2p<0><<<dim3(D_ / 128, M / 256), 512, 0, stream>>>(
            ctx_bf, wo_bf, bo + (size_t)L * D_,
            tmp_bf, nullptr, nullptr, nullptr, M, D_, D_);
        add_ln_kernel<<<M, 256, 0, stream>>>(tgt_bf, tmp_bf,
            ln1_g + (size_t)L * D_, ln1_b + (size_t)L * D_);
        gemm8p<256, 1><<<dim3(FF_ / 256, M / 256), 512, 0, stream>>>(
            tgt_bf, w1_bf, b1 + (size_t)L * FF_,
            ffh_bf, M, FF_, D_);
        gemm2p<0><<<dim3(D_ / 128, M / 256), 512, 0, stream>>>(
            ffh_bf, w2_bf, b2 + (size_t)L * D_,
            tmp_bf, nullptr, nullptr, nullptr, M, D_, FF_);
        add_ln_kernel<<<M, 256, 0, stream>>>(tgt_bf, tmp_bf,
            ln2_g + (size_t)L * D_, ln2_b + (size_t)L * D_);
    }

    head_kernel<<<B_, 256, 0, stream>>>(tgt_bf, W_ham, b_ham, head_out);
    loss_kernel<<<1, 256, 0, stream>>>(head_out, y, w, (float*)d_out);
}

// Round 9
// 1636.485 us; speedup vs baseline: 1.0372x; 1.0372x over previous
//
#include <hip/hip_runtime.h>
#include <math.h>

// ---------------------------------------------------------------------------
// TransformerContinuous: B=8, Lx=512, n_w=384, S=896, D=1024, H=16, hd=64,
// NL=4, FF=4096, HAM=144.
// Round 15: full revert to round-6 best (1638 us): QKV+FF1 on gemm8p BN=256
// 8-phase, Wo+FF2 on gemm2p BN=128 2-phase (round-3 schedule), attn QBLK=128.
// Rounds 7/8 proved both neighboring GEMM schedules regress. New: add_ln uses
// one-pass mean/variance (var = E[x^2]-mean^2): 6 barriers -> 2 per row.
// ---------------------------------------------------------------------------

#define B_      8
#define LX_     512
#define NW_     384
#define S_      896
#define D_      1024
#define H_      16
#define HD_     64
#define FF_     4096
#define HAM_    144

#define RMS_SCALE 0.9999500037496876f            // 1/sqrt(1.0001)
#define PE_C     (-6.907755278982137f / 1024.0f) // -ln(1000)/D

typedef __bf16 bf16x4 __attribute__((ext_vector_type(4)));
typedef __bf16 bf16x8 __attribute__((ext_vector_type(8)));
typedef float  f32x4  __attribute__((ext_vector_type(4)));

static __device__ __forceinline__ float nan0(float v) { return (v != v) ? 0.0f : v; }

static __device__ __forceinline__ void async_copy16(const __bf16* g, __bf16* l) {
    __builtin_amdgcn_global_load_lds(
        (const __attribute__((address_space(1))) void*)g,
        (__attribute__((address_space(3))) void*)l, 16, 0, 0);
}

// tanh-form GELU, one v_exp_f32; |err| vs exact-erf GELU < ~3e-4 (sub-bf16-ulp)
static __device__ __forceinline__ float fast_gelu(float x) {
    float x3 = x * x * x;
    float z = 0.7978845608028654f * x + 0.035677408136300125f * x3;
    float az = fabsf(z);
    float e = __expf(2.0f * az);
    float t = 1.0f - 2.0f / (e + 1.0f);
    t = (z < 0.0f) ? -t : t;
    return 0.5f * x * (1.0f + t);
}

// ---------------- fused fp32 -> bf16 conversion of 4 weight tensors ---------
__global__ __launch_bounds__(256) void convert4_kernel(
        const float* __restrict__ s0, const float* __restrict__ s1,
        const float* __restrict__ s2, const float* __restrict__ s3,
        __bf16* __restrict__ d0, __bf16* __restrict__ d1,
        __bf16* __restrict__ d2, __bf16* __restrict__ d3) {
    int blk = blockIdx.x;
    const float* src; __bf16* dst; int base;
    if (blk < 3072)      { src = s0; dst = d0; base = blk; }
    else if (blk < 4096) { src = s1; dst = d1; base = blk - 3072; }
    else if (blk < 8192) { src = s2; dst = d2; base = blk - 4096; }
    else                 { src = s3; dst = d3; base = blk - 8192; }
    int i = (base * 256 + threadIdx.x) * 4;
    float4 v = *(const float4*)&src[i];
    bf16x4 o = {(__bf16)v.x, (__bf16)v.y, (__bf16)v.z, (__bf16)v.w};
    *(bf16x4*)&dst[i] = o;
}

// ---------------- transpose W_nail (1024x63) -> W_nailT (63x1024) -----------
__global__ __launch_bounds__(256) void transpose_nail_kernel(
        const float* __restrict__ W_nail, float* __restrict__ WT) {
    int i = blockIdx.x * 256 + threadIdx.x;      // 63*1024 = 64512, grid 252
    int d = i & 1023, kk = i >> 10;
    WT[kk * 1024 + d] = W_nail[d * 63 + kk];
}

// ---------------- embed x: 8 rows per block, coalesced W_nailT ---------------
__global__ __launch_bounds__(256) void embed_x_kernel(
        const float* __restrict__ x, const float* __restrict__ WT,
        const float* __restrict__ b_nail, __bf16* __restrict__ tgt_bf,
        int* __restrict__ xmask) {
    int row0 = blockIdx.x * 8;               // 8 rows of (b*512+i)
    int tid = threadIdx.x;
    __shared__ float xn[8][64];
    __shared__ float ts[8];
#pragma unroll
    for (int it = 0; it < 2; ++it) {
        int i = tid + it * 256;              // 0..511
        int r = i >> 6, c = i & 63;
        float vv = x[(size_t)(row0 + r) * 64 + c];
        float v0 = nan0(vv);
        xn[r][c] = fminf(fmaxf(v0 * RMS_SCALE, -5.0f), 5.0f);
        if (c == 0) { ts[r] = v0; xmask[row0 + r] = (vv != vv) ? 1 : 0; }
    }
    __syncthreads();
    int d0 = tid * 4;
    float4 bz = *(const float4*)&b_nail[d0];
    float acc[8][4];
#pragma unroll
    for (int r = 0; r < 8; ++r) {
        acc[r][0] = bz.x; acc[r][1] = bz.y; acc[r][2] = bz.z; acc[r][3] = bz.w;
    }
    for (int k = 0; k < 63; ++k) {
        float4 wv = *(const float4*)&WT[k * 1024 + d0];
#pragma unroll
        for (int r = 0; r < 8; ++r) {
            float xv = xn[r][k + 1];         // block-uniform -> LDS broadcast
            acc[r][0] += xv * wv.x; acc[r][1] += xv * wv.y;
            acc[r][2] += xv * wv.z; acc[r][3] += xv * wv.w;
        }
    }
    float div[4];
#pragma unroll
    for (int j = 0; j < 4; ++j)
        div[j] = __expf((float)((d0 + j) >> 1) * PE_C);
#pragma unroll
    for (int r = 0; r < 8; ++r) {
        int row = row0 + r;
        int b = row >> 9, i = row & 511;
        float t = ts[r];
        bf16x4 ob;
#pragma unroll
        for (int j = 0; j < 4; ++j) {
            float ang = t * div[j];
            float pe = ((d0 + j) & 1) ? __cosf(ang) : __sinf(ang);
            ob[j] = (__bf16)(acc[r][j] + pe);
        }
        *(bf16x4*)&tgt_bf[((size_t)b * S_ + i) * D_ + d0] = ob;
    }
}

// ---------------- embed w: rows (b,j) of w -> tgt rows 512..895 ----------------
__global__ __launch_bounds__(256) void embed_w_kernel(
        const float* __restrict__ w, const float* __restrict__ W_cond,
        const float* __restrict__ b_cond, __bf16* __restrict__ tgt_bf) {
    int row = blockIdx.x;              // b*384 + j
    int b = row / NW_, j = row % NW_;
    const float* wr = w + (long)row * 6;
    float wn[6];
#pragma unroll
    for (int k = 0; k < 6; ++k)
        wn[k] = fminf(fmaxf(nan0(wr[k]) * RMS_SCALE, -5.0f), 5.0f);
    int tid = threadIdx.x;
    int d0 = tid * 4;
    float pos = (float)(LX_ + j);
    bf16x4 ob;
#pragma unroll
    for (int jj = 0; jj < 4; ++jj) {
        int d = d0 + jj;
        float acc = b_cond[d];
        const float* wc = W_cond + (long)d * 6;
#pragma unroll
        for (int k = 0; k < 6; ++k) acc += wn[k] * wc[k];
        float dv = expf((float)(d >> 1) * PE_C);
        float ang = pos * dv;
        ob[jj] = (__bf16)(acc + ((d & 1) ? cosf(ang) : sinf(ang)));
    }
    *(bf16x4*)&tgt_bf[((long)b * S_ + LX_ + j) * D_ + d0] = ob;
}

// ---------------------------------------------------------------------------
// Shared GEMM macros. C[M,N] = A[M,K] @ W[N,K]^T + bias.
//   A frag mi (0..7): row = (mi>>2)*128 + wr*64 + (mi&3)*16
//   B frag ni:  BN=256: row = (ni>>1)*128 + wc*32 + (ni&1)*16
//               BN=128: row = ni*64 + wc*16
// ---------------------------------------------------------------------------

#define LDA(BUF, MH) do {                                                      \
    _Pragma("unroll")                                                          \
    for (int i_ = 0; i_ < 4; ++i_) {                                           \
        const int row_ = (MH) * 128 + wr * 64 + i_ * 16 + frow;                \
        _Pragma("unroll")                                                      \
        for (int k_ = 0; k_ < 2; ++k_)                                         \
            a[i_][k_] = *(const bf16x8*)&As[BUF][row_ * 64 +                   \
                (((quad + k_ * 4) ^ sf) * 8)];                                 \
    }                                                                          \
} while (0)

#define LDB(BUF, NH) do {                                                      \
    _Pragma("unroll")                                                          \
    for (int j_ = 0; j_ < NJ; ++j_) {                                          \
        const int row_ = (BN == 256)                                           \
            ? ((NH) * 128 + j_ * 16 + wc * 32 + frow)                          \
            : ((NH) * 64 + wc * 16 + frow);                                    \
        _Pragma("unroll")                                                      \
        for (int k_ = 0; k_ < 2; ++k_)                                         \
            b[(NH) * NJ + j_][k_] = *(const bf16x8*)&Bs[BUF][row_ * 64 +       \
                (((quad + k_ * 4) ^ sf) * 8)];                                 \
    }                                                                          \
} while (0)

#define MMA(MH, NH) do {                                                       \
    _Pragma("unroll")                                                          \
    for (int i_ = 0; i_ < 4; ++i_)                                             \
        _Pragma("unroll")                                                      \
        for (int j_ = 0; j_ < NJ; ++j_)                                        \
            _Pragma("unroll")                                                  \
            for (int k_ = 0; k_ < 2; ++k_)                                     \
                acc[(MH) * 4 + i_][(NH) * NJ + j_] =                           \
                    __builtin_amdgcn_mfma_f32_16x16x32_bf16(                   \
                        b[(NH) * NJ + j_][k_], a[i_][k_],                      \
                        acc[(MH) * 4 + i_][(NH) * NJ + j_], 0, 0, 0);          \
} while (0)

#define STAGE_A(BUF, H, KT) do {                                               \
    const __bf16* g_ = Ag + (size_t)((H) * 128) * K + ((size_t)(KT) << 6);     \
    async_copy16(g_, &As[BUF][((H) * 128) * 64 + dst8]);                       \
    async_copy16(g_ + ((size_t)K << 6), &As[BUF][((H) * 128 + 64) * 64 + dst8]); \
} while (0)

#define STAGE_B(BUF, H, KT) do {                                               \
    if constexpr (BN == 256) {                                                 \
        const __bf16* g_ = Wg + (size_t)((H) * 128) * K + ((size_t)(KT) << 6); \
        async_copy16(g_, &Bs[BUF][((H) * 128) * 64 + dst8]);                   \
        async_copy16(g_ + ((size_t)K << 6),                                    \
                     &Bs[BUF][((H) * 128 + 64) * 64 + dst8]);                  \
    } else {                                                                   \
        const __bf16* g_ = Wg + (size_t)((H) * 64) * K + ((size_t)(KT) << 6);  \
        async_copy16(g_, &Bs[BUF][((H) * 64) * 64 + dst8]);                    \
    }                                                                          \
} while (0)

#define PHASE_SYNC() do {                                                      \
    __builtin_amdgcn_sched_barrier(0);                                         \
    __builtin_amdgcn_s_barrier();                                              \
    asm volatile("s_waitcnt lgkmcnt(0)" ::: "memory");                         \
    __builtin_amdgcn_sched_barrier(0);                                         \
} while (0)

#define PHASE_END() do {                                                       \
    __builtin_amdgcn_sched_barrier(0);                                         \
    __builtin_amdgcn_s_barrier();                                              \
} while (0)

#define VM_MAIN do {                                                           \
    if constexpr (BN == 256) { asm volatile("s_waitcnt vmcnt(6)" ::: "memory"); } \
    else                     { asm volatile("s_waitcnt vmcnt(4)" ::: "memory"); } \
} while (0)
#define VM_ZERO asm volatile("s_waitcnt vmcnt(0)" ::: "memory")
#define VM_NONE ((void)0)

// 8-phase K-tile for BN=256 (round-6 benched)
#define GTILE(S1, S2, VMOP) do {                                               \
    const int bf_ = t & 1;                                                     \
    LDA(bf_, 0); LDB(bf_, 0);                                                  \
    if (S1) STAGE_A(bf_ ^ 1, 1, t + 1);                                        \
    PHASE_SYNC();                                                              \
    __builtin_amdgcn_s_setprio(1); MMA(0, 0); __builtin_amdgcn_s_setprio(0);   \
    PHASE_END();                                                               \
    LDB(bf_, 1);                                                               \
    if (S2) STAGE_B(bf_, 0, t + 2);                                            \
    PHASE_SYNC();                                                              \
    __builtin_amdgcn_s_setprio(1); MMA(0, 1); __builtin_amdgcn_s_setprio(0);   \
    PHASE_END();                                                               \
    LDA(bf_, 1);                                                               \
    if (S2) STAGE_A(bf_, 0, t + 2);                                            \
    PHASE_SYNC();                                                              \
    __builtin_amdgcn_s_setprio(1); MMA(1, 0); __builtin_amdgcn_s_setprio(0);   \
    PHASE_END();                                                               \
    if (S2) STAGE_B(bf_, 1, t + 2);                                            \
    VMOP;                                                                      \
    PHASE_SYNC();                                                              \
    __builtin_amdgcn_s_setprio(1); MMA(1, 1); __builtin_amdgcn_s_setprio(0);   \
    PHASE_END();                                                               \
} while (0)

// ---------------- 8-phase BN=256 pipelined GEMM (QKV / FF1) -----------------
// MODE 1: bias+GELU   MODE 2: bias, split q/k (B,H,S,64), V transposed (B,H,64,S)
template <int BN, int MODE>
__global__ __launch_bounds__(512, 2) void gemm8p(
        const __bf16* __restrict__ A, const __bf16* __restrict__ W,
        const float* __restrict__ bias,
        __bf16* __restrict__ Cb,
        __bf16* __restrict__ Cq, __bf16* __restrict__ Ck, __bf16* __restrict__ Cv,
        int M, int N, int K) {
    constexpr int NI = BN / 64;          // per-wave n-frags (4 or 2)
    constexpr int NJ = NI / 2;           // n-frags per n-half (2 or 1)
    static_assert(BN == 256 || BN == 128, "BN");
    __shared__ __attribute__((aligned(16))) __bf16 As[2][256 * 64];
    __shared__ __attribute__((aligned(16))) __bf16 Bs[2][BN * 64];

    const int tid = threadIdx.x;
    const int wave = tid >> 6, lane = tid & 63;
    const int wr = wave >> 2, wc = wave & 3;
    const int frow = lane & 15, quad = lane >> 4;
    const int sf = frow & 7;

    // XCD-chunked block swizzle (nwg % 8 == 0 for all our grids)
    const int nwg = gridDim.x * gridDim.y;
    int orig = blockIdx.y * gridDim.x + blockIdx.x;
    int tile = orig;
    if ((nwg & 7) == 0) tile = (orig & 7) * (nwg >> 3) + (orig >> 3);
    const int m0 = (tile / gridDim.x) * 256;
    const int n0 = (tile % gridDim.x) * BN;

    const int sr = tid >> 3;
    const int scol = ((tid & 7) ^ (sr & 7)) * 8;
    const __bf16* Ag = A + (size_t)(m0 + sr) * K + scol;
    const __bf16* Wg = W + (size_t)(n0 + sr) * K + scol;
    const int dst8 = tid * 8;            // elements; = tid*16 bytes (linear)

    f32x4 acc[8][NI];
#pragma unroll
    for (int i = 0; i < 8; ++i)
#pragma unroll
        for (int j = 0; j < NI; ++j) acc[i][j] = 0.0f;
    bf16x8 a[4][2];
    bf16x8 b[NI][2];

    const int NT = K >> 6;

    STAGE_B(0, 0, 0); STAGE_A(0, 0, 0); STAGE_B(0, 1, 0); STAGE_A(0, 1, 0);
    STAGE_B(1, 0, 1); STAGE_A(1, 0, 1); STAGE_B(1, 1, 1);
    VM_MAIN;                             // tile 0 fully landed
    __builtin_amdgcn_s_barrier();

    int t = 0;
    for (; t < NT - 2; ++t) { GTILE(1, 1, VM_MAIN); }
    GTILE(1, 0, VM_ZERO);
    ++t;
    GTILE(0, 0, VM_NONE);

    // ---------------- epilogue ----------------
#pragma unroll
    for (int ni = 0; ni < NI; ++ni) {
        int cg0;
        if constexpr (BN == 256)
            cg0 = n0 + (ni >> 1) * 128 + (ni & 1) * 16 + wc * 32 + quad * 4;
        else
            cg0 = n0 + ni * 64 + wc * 16 + quad * 4;
        float4 bv = *(const float4*)&bias[cg0];
        float bz[4] = {bv.x, bv.y, bv.z, bv.w};
#pragma unroll
        for (int mi = 0; mi < 8; ++mi) {
            int rg = m0 + (mi >> 2) * 128 + wr * 64 + (mi & 3) * 16 + frow;
            float vv[4];
#pragma unroll
            for (int r = 0; r < 4; ++r) {
                float v = acc[mi][ni][r] + bz[r];
                if (MODE == 1) v = fast_gelu(v);
                vv[r] = v;
            }
            if (MODE == 2) {
                int which = cg0 >> 10;        // 0=q 1=k 2=v
                int h = (cg0 & 1023) >> 6;
                int e = cg0 & 63;
                int bb = rg / S_, s = rg % S_;
                if (which == 2) {
                    // V transposed: vt[(b,h,e,s)]
                    size_t vb = ((size_t)bb * H_ + h) * HD_ + e;
#pragma unroll
                    for (int r = 0; r < 4; ++r)
                        Cv[(vb + r) * S_ + s] = (__bf16)vv[r];
                } else {
                    bf16x4 o = {(__bf16)vv[0], (__bf16)vv[1], (__bf16)vv[2], (__bf16)vv[3]};
                    __bf16* dstp = (which == 0) ? Cq : Ck;
                    *(bf16x4*)&dstp[(((size_t)bb * H_ + h) * S_ + s) * HD_ + e] = o;
                }
            } else {
                bf16x4 o = {(__bf16)vv[0], (__bf16)vv[1], (__bf16)vv[2], (__bf16)vv[3]};
                *(bf16x4*)&Cb[(size_t)rg * N + cg0] = o;
            }
        }
    }
}

// ---------------- 2-phase BN=128 pipelined GEMM (Wo / FF2, MODE 0) ----------
// (round-3-benched version) Per phase: 16 MFMA. Single vmcnt(4) per K-tile.
// XCD-chunked swizzle: each XCD owns contiguous tiles (A-panel L2 reuse).
__global__ __launch_bounds__(512, 2) void gemm2p(
        const __bf16* __restrict__ A, const __bf16* __restrict__ W,
        const float* __restrict__ bias, __bf16* __restrict__ Cb,
        int M, int N, int K) {
    constexpr int BN = 128;
    constexpr int NI = 2, NJ = 1;
    __shared__ __attribute__((aligned(16))) __bf16 As[2][256 * 64];
    __shared__ __attribute__((aligned(16))) __bf16 Bs[2][128 * 64];

    const int tid = threadIdx.x;
    const int wave = tid >> 6, lane = tid & 63;
    const int wr = wave >> 2, wc = wave & 3;
    const int frow = lane & 15, quad = lane >> 4;
    const int sf = frow & 7;

    // XCD-chunked block swizzle (requires nwg % 8 == 0, true for our grids)
    const int nwg = gridDim.x * gridDim.y;
    int orig = blockIdx.y * gridDim.x + blockIdx.x;
    int tile = orig;
    if ((nwg & 7) == 0) tile = (orig & 7) * (nwg >> 3) + (orig >> 3);
    const int m0 = (tile / gridDim.x) * 256;
    const int n0 = (tile % gridDim.x) * BN;

    const int sr = tid >> 3;
    const int scol = ((tid & 7) ^ (sr & 7)) * 8;
    const __bf16* Ag = A + (size_t)(m0 + sr) * K + scol;
    const __bf16* Wg = W + (size_t)(n0 + sr) * K + scol;
    const int dst8 = tid * 8;

    f32x4 acc[8][NI];
#pragma unroll
    for (int i = 0; i < 8; ++i)
#pragma unroll
        for (int j = 0; j < NI; ++j) acc[i][j] = 0.0f;
    bf16x8 a[4][2];
    bf16x8 b[NI][2];

    const int NT = K >> 6;

#define VM4 asm volatile("s_waitcnt vmcnt(4)" ::: "memory")
#define GTILE2(S1, S2, VMOP) do {                                              \
    const int bf_ = t & 1;                                                     \
    /* P0: read A0 + both B halves; stage a1_{t+1} into other buffer */        \
    LDA(bf_, 0); LDB(bf_, 0); LDB(bf_, 1);                                     \
    if (S1) STAGE_A(bf_ ^ 1, 1, t + 1);                                        \
    PHASE_SYNC();                                                              \
    __builtin_amdgcn_s_setprio(1); MMA(0, 0); MMA(0, 1);                       \
    __builtin_amdgcn_s_setprio(0);                                             \
    PHASE_END();                                                               \
    /* P1: read A1; stage b_{t+2} + a0_{t+2} into this buffer (dead slots) */  \
    LDA(bf_, 1);                                                               \
    if (S2) { STAGE_B(bf_, 0, t + 2); STAGE_B(bf_, 1, t + 2);                  \
              STAGE_A(bf_, 0, t + 2); }                                        \
    VMOP;                                                                      \
    PHASE_SYNC();                                                              \
    __builtin_amdgcn_s_setprio(1); MMA(1, 0); MMA(1, 1);                       \
    __builtin_amdgcn_s_setprio(0);                                             \
    PHASE_END();                                                               \
} while (0)

    // prologue queue: b_0(2), a0_0(2), a1_0(2), b_1(2), a0_1(2)
    STAGE_B(0, 0, 0); STAGE_B(0, 1, 0); STAGE_A(0, 0, 0); STAGE_A(0, 1, 0);
    STAGE_B(1, 0, 1); STAGE_B(1, 1, 1); STAGE_A(1, 0, 1);
    VM4;                                 // drain through a1_0: tile 0 landed
    __builtin_amdgcn_s_barrier();

    int t = 0;
    for (; t < NT - 2; ++t) { GTILE2(1, 1, VM4); }
    GTILE2(1, 0, VM_ZERO);               // drains a1_{NT-1}: last tile landed
    ++t;
    GTILE2(0, 0, VM_NONE);
#undef GTILE2
#undef VM4

    // ---------------- epilogue (bias only) ----------------
#pragma unroll
    for (int ni = 0; ni < NI; ++ni) {
        int cg0 = n0 + ni * 64 + wc * 16 + quad * 4;
        float4 bv = *(const float4*)&bias[cg0];
        float bz[4] = {bv.x, bv.y, bv.z, bv.w};
#pragma unroll
        for (int mi = 0; mi < 8; ++mi) {
            int rg = m0 + (mi >> 2) * 128 + wr * 64 + (mi & 3) * 16 + frow;
            bf16x4 o;
#pragma unroll
            for (int r = 0; r < 4; ++r) o[r] = (__bf16)(acc[mi][ni][r] + bz[r]);
            *(bf16x4*)&Cb[(size_t)rg * N + cg0] = o;
        }
    }
}

// ---------------- MFMA flash attention: QBLK=128, 8 waves, 1 barrier/tile ---
// K (b,h,s,64) and Vt (b,h,64,s) staged via global_load_lds (XOR-swizzled,
// double-buffered) once per block, shared by 8 waves. Stage of tile t+1 is
// issued AFTER the top barrier of tile t into the buffer whose reads all
// completed BEFORE that barrier -> single barrier per k-tile.
// Wave-level skip of fully-masked tiles; flavors: x-mask / no-mask / diag.
__global__ __launch_bounds__(512, 4) void attn_mfma(
        const __bf16* __restrict__ q, const __bf16* __restrict__ k,
        const __bf16* __restrict__ vt, const int* __restrict__ xmask,
        __bf16* __restrict__ ctx) {
    __shared__ __attribute__((aligned(16))) __bf16 Ks[2][64 * 64];
    __shared__ __attribute__((aligned(16))) __bf16 Vs[2][64 * 64];
    __shared__ __attribute__((aligned(16))) __bf16 Ps[8][16 * 64];
    __shared__ float mb[LX_];           // x-mask bias: 0 or -inf
    int tid = threadIdx.x;
    int wave = tid >> 6, lane = tid & 63;
    int frow = lane & 15, quad = lane >> 4;
    int f7 = frow & 7, f3 = frow >> 3;
    int sl0 = (quad ^ f7) * 8;          // slot for k-elems 0..31
    int sl1 = ((quad + 4) ^ f7) * 8;    // slot for k-elems 32..63

    // XCD swizzle: 896 blocks = 8 xcd * 112 slots; 16 bh per xcd, 7 qt each.
    int blk = blockIdx.x;
    int xcd = blk & 7, slot = blk >> 3;  // slot 0..111
    int bh = xcd * 16 + slot / 7;
    int qt = slot % 7;
    int b = bh >> 4, h = bh & 15;
    int q0 = qt * 128;
    int q0w = q0 + wave * 16;            // this wave's 16 q-rows start
    size_t base = (size_t)bh * S_ * HD_;   // q,k layout
    size_t vbase = (size_t)bh * HD_ * S_;  // vt layout (same extent)

    for (int i = tid; i < LX_; i += 512)
        mb[i] = xmask[(b << 9) + i] ? -INFINITY : 0.0f;

    const __bf16* qrow = q + base + (size_t)(q0w + frow) * HD_ + quad * 8;
    bf16x8 aq0 = *(const bf16x8*)qrow;
    bf16x8 aq1 = *(const bf16x8*)(qrow + 32);

    f32x4 o[4];
#pragma unroll
    for (int dt = 0; dt < 4; ++dt) o[dt] = 0.0f;
    float mrow[4] = {-INFINITY, -INFINITY, -INFINITY, -INFINITY};
    float lrow[4] = {0.0f, 0.0f, 0.0f, 0.0f};

    int kend = (q0 >= LX_) ? (q0 + 128) : LX_;
    int NT = kend >> 6;

    // staging: thread -> (row tid>>3 of 64, slot tid&7), pre-swizzled col
    int sr = tid >> 3;                   // 0..63
    int kcol = ((tid & 7) ^ (sr & 7)) * 8;
    const __bf16* kg = k + base + (size_t)sr * HD_ + kcol;
    const __bf16* vg = vt + vbase + (size_t)sr * S_ + kcol;

#define ASTAGE(BUF, K0) do {                                                   \
    async_copy16(kg + (size_t)(K0) * HD_, &Ks[BUF][tid * 8]);                  \
    async_copy16(vg + (K0),               &Vs[BUF][tid * 8]);                  \
} while (0)

    ASTAGE(0, 0);
    __syncthreads();    // drains vmcnt: tile 0 landed; mb visible

    for (int t = 0; t < NT; ++t) {
        int buf = t & 1;
        int k0 = t << 6;
        // tile t landed (its 2 loads are the only outstanding vmem)
        asm volatile("s_waitcnt vmcnt(0)" ::: "memory");
        __builtin_amdgcn_s_barrier();    // separates tile t-1 reads from stage
        __builtin_amdgcn_sched_barrier(0);
        if (t + 1 < NT) ASTAGE(buf ^ 1, k0 + 64);   // into dead buffer

        // wave-level skip: fully-masked w-region tile for this wave
        if (k0 < LX_ || q0w + 15 >= k0) {
            // ---- QK^T ----
            f32x4 scr[4];
            __builtin_amdgcn_s_setprio(1);
#pragma unroll
            for (int nt = 0; nt < 4; ++nt) {
                int row = (nt * 16 + frow) * 64;
                bf16x8 bk0 = *(const bf16x8*)&Ks[buf][row + sl0];
                bf16x8 bk1 = *(const bf16x8*)&Ks[buf][row + sl1];
                f32x4 z = 0.0f;
                z = __builtin_amdgcn_mfma_f32_16x16x32_bf16(aq0, bk0, z, 0, 0, 0);
                z = __builtin_amdgcn_mfma_f32_16x16x32_bf16(aq1, bk1, z, 0, 0, 0);
                scr[nt] = z;
            }
            __builtin_amdgcn_s_setprio(0);

            // ---- masked scale, per tile flavor ----
            float tmax[4] = {-INFINITY, -INFINITY, -INFINITY, -INFINITY};
            if (k0 < LX_) {              // x-region cols: x_mask bias only
#pragma unroll
                for (int nt = 0; nt < 4; ++nt) {
                    float bias = mb[k0 + nt * 16 + frow];
#pragma unroll
                    for (int r = 0; r < 4; ++r) {
                        float s = scr[nt][r] * 0.125f + bias;
                        scr[nt][r] = s;
                        tmax[r] = fmaxf(tmax[r], s);
                    }
                }
            } else if (q0w >= k0 + 64) { // strictly below diagonal
#pragma unroll
                for (int nt = 0; nt < 4; ++nt)
#pragma unroll
                    for (int r = 0; r < 4; ++r) {
                        float s = scr[nt][r] * 0.125f;
                        scr[nt][r] = s;
                        tmax[r] = fmaxf(tmax[r], s);
                    }
            } else {                     // diagonal tile: causal
#pragma unroll
                for (int nt = 0; nt < 4; ++nt) {
                    int kj = k0 + nt * 16 + frow;
#pragma unroll
                    for (int r = 0; r < 4; ++r) {
                        float s = scr[nt][r] * 0.125f;
                        if (kj > q0w + quad * 4 + r) s = -INFINITY;
                        scr[nt][r] = s;
                        tmax[r] = fmaxf(tmax[r], s);
                    }
                }
            }
#pragma unroll
            for (int off = 1; off < 16; off <<= 1)
#pragma unroll
                for (int r = 0; r < 4; ++r)
                    tmax[r] = fmaxf(tmax[r], __shfl_xor(tmax[r], off, 64));

            float alpha[4], rsum[4];
#pragma unroll
            for (int r = 0; r < 4; ++r) {
                float nm = fmaxf(mrow[r], tmax[r]);
                alpha[r] = (nm == -INFINITY) ? 1.0f : __expf(mrow[r] - nm);
                mrow[r] = nm;
                rsum[r] = 0.0f;
            }
#pragma unroll
            for (int nt = 0; nt < 4; ++nt) {
#pragma unroll
                for (int r = 0; r < 4; ++r) {
                    float s = scr[nt][r];
                    float p = (s == -INFINITY) ? 0.0f : __expf(s - mrow[r]);
                    rsum[r] += p;
                    // Ps[q_local][col] with col-slot XOR swizzle
                    int ql = quad * 4 + r;
                    int pslot = ((nt * 2 + f3) ^ (ql & 7)) * 8 + f7;
                    Ps[wave][ql * 64 + pslot] = (__bf16)p;
                }
            }
#pragma unroll
            for (int off = 1; off < 16; off <<= 1)
#pragma unroll
                for (int r = 0; r < 4; ++r)
                    rsum[r] += __shfl_xor(rsum[r], off, 64);
#pragma unroll
            for (int r = 0; r < 4; ++r)
                lrow[r] = lrow[r] * alpha[r] + rsum[r];
#pragma unroll
            for (int dt = 0; dt < 4; ++dt)
#pragma unroll
                for (int r = 0; r < 4; ++r)
                    o[dt][r] *= alpha[r];

            // ---- PV ----
            bf16x8 ap0 = *(const bf16x8*)&Ps[wave][frow * 64 + sl0];
            bf16x8 ap1 = *(const bf16x8*)&Ps[wave][frow * 64 + sl1];
            __builtin_amdgcn_s_setprio(1);
#pragma unroll
            for (int dt = 0; dt < 4; ++dt) {
                int row = (dt * 16 + frow) * 64;
                bf16x8 bv0 = *(const bf16x8*)&Vs[buf][row + sl0];
                bf16x8 bv1 = *(const bf16x8*)&Vs[buf][row + sl1];
                o[dt] = __builtin_amdgcn_mfma_f32_16x16x32_bf16(ap0, bv0, o[dt], 0, 0, 0);
                o[dt] = __builtin_amdgcn_mfma_f32_16x16x32_bf16(ap1, bv1, o[dt], 0, 0, 0);
            }
            __builtin_amdgcn_s_setprio(0);
        }
        __builtin_amdgcn_sched_barrier(0);
    }
#undef ASTAGE

#pragma unroll
    for (int r = 0; r < 4; ++r) {
        float inv = (lrow[r] > 0.0f) ? 1.0f / lrow[r] : 0.0f;
        int qg = q0w + quad * 4 + r;
        size_t ob = ((size_t)b * S_ + qg) * D_ + h * HD_;
#pragma unroll
        for (int dt = 0; dt < 4; ++dt)
            ctx[ob + dt * 16 + frow] = (__bf16)(o[dt][r] * inv);
    }
}

// ---------------- fused residual add + LayerNorm (one-pass stats) -----------
__global__ __launch_bounds__(256) void add_ln_kernel(
        __bf16* __restrict__ xs_bf, const __bf16* __restrict__ o,
        const float* __restrict__ g, const float* __restrict__ bb) {
    long row = blockIdx.x;
    __bf16* xr = xs_bf + row * D_;
    const __bf16* orr = o + row * D_;
    int tid = threadIdx.x;
    bf16x4 a4 = *(const bf16x4*)&xr[tid * 4];
    bf16x4 b4v = *(const bf16x4*)&orr[tid * 4];
    float vv[4];
#pragma unroll
    for (int j = 0; j < 4; ++j) vv[j] = (float)a4[j] + (float)b4v[j];
    float s = vv[0] + vv[1] + vv[2] + vv[3];
    float s2 = vv[0] * vv[0] + vv[1] * vv[1] + vv[2] * vv[2] + vv[3] * vv[3];
    __shared__ float red[4], red2[4];
    __shared__ float stat, stat2;
#pragma unroll
    for (int off = 32; off; off >>= 1) {
        s += __shfl_down(s, off, 64);
        s2 += __shfl_down(s2, off, 64);
    }
    if ((tid & 63) == 0) { red[tid >> 6] = s; red2[tid >> 6] = s2; }
    __syncthreads();
    if (tid == 0) {
        stat = (red[0] + red[1] + red[2] + red[3]) * (1.0f / 1024.0f);
        stat2 = (red2[0] + red2[1] + red2[2] + red2[3]) * (1.0f / 1024.0f);
    }
    __syncthreads();
    float mean = stat;
    float var = stat2 - mean * mean;
    float inv = 1.0f / sqrtf(var + 1e-5f);
    float4 gg = *(const float4*)&g[tid * 4];
    float4 bv = *(const float4*)&bb[tid * 4];
    float g4[4] = {gg.x, gg.y, gg.z, gg.w};
    float b4[4] = {bv.x, bv.y, bv.z, bv.w};
    bf16x4 ob;
#pragma unroll
    for (int j = 0; j < 4; ++j)
        ob[j] = (__bf16)((vv[j] - mean) * inv * g4[j] + b4[j]);
    *(bf16x4*)&xr[tid * 4] = ob;
}

// ---------------- head: (8,1024) @ W_ham^T + b_ham -> (8,144) ----------------
__global__ __launch_bounds__(256) void head_kernel(
        const __bf16* __restrict__ tgt_bf, const float* __restrict__ W_ham,
        const float* __restrict__ b_ham, float* __restrict__ out) {
    int b = blockIdx.x;
    int tid = threadIdx.x;
    __shared__ float xr[D_];
    const __bf16* row = tgt_bf + ((long)b * S_ + (S_ - 1)) * D_;
    for (int i = tid; i < D_; i += 256) xr[i] = (float)row[i];
    __syncthreads();
    for (int n = tid; n < HAM_; n += 256) {
        float acc = b_ham[n];
        const float* wr = W_ham + (long)n * D_;
        for (int kk = 0; kk < D_; ++kk) acc += xr[kk] * wr[kk];
        out[b * HAM_ + n] = acc;
    }
}

// ---------------- loss: mean((head_out - (y - w_last))^2) --------------------
__global__ __launch_bounds__(256) void loss_kernel(
        const float* __restrict__ head_out, const float* __restrict__ y,
        const float* __restrict__ w, float* __restrict__ out) {
    int tid = threadIdx.x;
    float acc = 0.0f;
    for (int i = tid; i < B_ * HAM_; i += 256) {
        int b = i / HAM_, r = i % HAM_;
        float w_last = w[((long)b * 16 + 15) * HAM_ + r];
        float resid = y[i] - w_last;
        float dd = head_out[i] - resid;
        acc += dd * dd;
    }
    __shared__ float red[4];
#pragma unroll
    for (int off = 32; off; off >>= 1) acc += __shfl_down(acc, off, 64);
    if ((tid & 63) == 0) red[tid >> 6] = acc;
    __syncthreads();
    if (tid == 0)
        out[0] = (red[0] + red[1] + red[2] + red[3]) * (1.0f / (B_ * HAM_));
}

// ---------------------------------------------------------------------------
extern "C" void kernel_launch(void* const* d_in, const int* in_sizes, int n_in,
                              void* d_out, int out_size, void* d_ws, size_t ws_size,
                              hipStream_t stream) {
    const float* x      = (const float*)d_in[0];
    const float* w      = (const float*)d_in[1];
    const float* y      = (const float*)d_in[2];
    const float* W_nail = (const float*)d_in[3];
    const float* b_nail = (const float*)d_in[4];
    const float* W_cond = (const float*)d_in[5];
    const float* b_cond = (const float*)d_in[6];
    const float* Wqkv   = (const float*)d_in[7];
    const float* bqkv   = (const float*)d_in[8];
    const float* Wo     = (const float*)d_in[9];
    const float* bo     = (const float*)d_in[10];
    const float* ln1_g  = (const float*)d_in[11];
    const float* ln1_b  = (const float*)d_in[12];
    const float* ln2_g  = (const float*)d_in[13];
    const float* ln2_b  = (const float*)d_in[14];
    const float* W1     = (const float*)d_in[15];
    const float* b1     = (const float*)d_in[16];
    const float* W2     = (const float*)d_in[17];
    const float* b2     = (const float*)d_in[18];
    const float* W_ham  = (const float*)d_in[19];
    const float* b_ham  = (const float*)d_in[20];

    float* ws = (float*)d_ws;
    const long SEG = (long)B_ * S_ * D_;            // 7,340,032 floats
    float*  W_nailT = ws;                           // 64512 floats (in old tgt slot)
    __bf16* tmp_bf = (__bf16*)(ws + SEG);           // [SEG, 1.5SEG)
    __bf16* tgt_bf = (__bf16*)(ws + 2 * SEG);       // [2SEG, 2.5SEG)
    __bf16* ctx_bf = (__bf16*)(ws + 2 * SEG + SEG / 2);      // [2.5SEG, 3SEG)
    __bf16* qb     = (__bf16*)(ws + 3 * SEG);                // [3SEG, 3.5SEG)
    __bf16* kb     = (__bf16*)(ws + 3 * SEG + SEG / 2);      // [3.5SEG, 4SEG)
    __bf16* vb     = (__bf16*)(ws + 4 * SEG);                // [4SEG, 4.5SEG) (transposed)
    __bf16* ffh_bf = (__bf16*)(ws + 2 * SEG + SEG / 2);      // overlays ctx|q|k|v
    __bf16* wbf    = (__bf16*)(ws + 4 * SEG + SEG / 2);      // 12.58M bf16
    int*    xmask    = (int*)(ws + 4 * SEG + SEG / 2 + 6291456);
    float*  head_out = ws + 4 * SEG + SEG / 2 + 6291456 + 4096;

    __bf16* wqkv_bf = wbf;
    __bf16* wo_bf   = wbf + 3145728;
    __bf16* w1_bf   = wbf + 4194304;
    __bf16* w2_bf   = wbf + 8388608;

    const int M = B_ * S_;                          // 7168

    transpose_nail_kernel<<<252, 256, 0, stream>>>(W_nail, W_nailT);
    embed_x_kernel<<<B_ * LX_ / 8, 256, 0, stream>>>(x, W_nailT, b_nail, tgt_bf, xmask);
    embed_w_kernel<<<B_ * NW_, 256, 0, stream>>>(w, W_cond, b_cond, tgt_bf);

    for (int L = 0; L < 4; ++L) {
        const int NQ = 3 * D_ * D_, NO = D_ * D_, N1 = FF_ * D_, N2 = D_ * FF_;
        convert4_kernel<<<12288, 256, 0, stream>>>(
            Wqkv + (size_t)L * NQ, Wo + (size_t)L * NO,
            W1 + (size_t)L * N1, W2 + (size_t)L * N2,
            wqkv_bf, wo_bf, w1_bf, w2_bf);

        gemm8p<256, 2><<<dim3(3 * D_ / 256, M / 256), 512, 0, stream>>>(
            tgt_bf, wqkv_bf, bqkv + (size_t)L * 3 * D_,
            nullptr, qb, kb, vb, M, 3 * D_, D_);
        attn_mfma<<<B_ * H_ * (S_ / 128), 512, 0, stream>>>(qb, kb, vb, xmask, ctx_bf);
        gemm2p<<<dim3(D_ / 128, M / 256), 512, 0, stream>>>(
            ctx_bf, wo_bf, bo + (size_t)L * D_, tmp_bf, M, D_, D_);
        add_ln_kernel<<<M, 256, 0, stream>>>(tgt_bf, tmp_bf,
            ln1_g + (size_t)L * D_, ln1_b + (size_t)L * D_);
        gemm8p<256, 1><<<dim3(FF_ / 256, M / 256), 512, 0, stream>>>(
            tgt_bf, w1_bf, b1 + (size_t)L * FF_,
            ffh_bf, nullptr, nullptr, nullptr, M, FF_, D_);
        gemm2p<<<dim3(D_ / 128, M / 256), 512, 0, stream>>>(
            ffh_bf, w2_bf, b2 + (size_t)L * D_, tmp_bf, M, D_, FF_);
        add_ln_kernel<<<M, 256, 0, stream>>>(tgt_bf, tmp_bf,
            ln2_g + (size_t)L * D_, ln2_b + (size_t)L * D_);
    }

    head_kernel<<<B_, 256, 0, stream>>>(tgt_bf, W_ham, b_ham, head_out);
    loss_kernel<<<1, 256, 0, stream>>>(head_out, y, w, (float*)d_out);
}